// Round 14
// baseline (776.653 us; speedup 1.0000x reference)
//
#include <hip/hip_runtime.h>
#include <math.h>

#define B_   16
#define S_   200
#define H_   400
#define V_   25000
#define T_   8
#define NS_  30
#define NB_  3
#define BS_  480   // NS_*B_

#define KP_  448   // K padded (7 tiles of 64)
#define MP_  512
#define NP_  25088 // vocab N padded (196 tiles of 128)
#define NG_  1280  // gates N padded (10 tiles of 128)
#define MA_  3840  // T_*BS_
#define NVT_ (NP_/128)   // 196
#define PSL_ 200

typedef unsigned short u16;
typedef __attribute__((ext_vector_type(4))) float f32x4;
typedef __attribute__((ext_vector_type(8))) short short8;

__device__ __forceinline__ u16 f2bf(float f) {
    unsigned u = __float_as_uint(f);
    u += 0x7FFFu + ((u >> 16) & 1u);
    return (u16)(u >> 16);
}
__device__ __forceinline__ float bf2f(u16 v) {
    return __uint_as_float(((unsigned)v) << 16);
}
__device__ __forceinline__ float sigm(float x) {
    return 1.f / (1.f + __expf(-x));
}
__device__ __forceinline__ float ftanh(float x) {
    float e2 = __expf(2.f * x);
    return 1.f - 2.f / (e2 + 1.f);
}
__device__ __forceinline__ float wred_sum(float v) {
    v += __shfl_xor(v, 32); v += __shfl_xor(v, 16); v += __shfl_xor(v, 8);
    v += __shfl_xor(v, 4);  v += __shfl_xor(v, 2);  v += __shfl_xor(v, 1);
    return v;
}
__device__ __forceinline__ float wred_max(float v) {
    v = fmaxf(v, __shfl_xor(v, 32)); v = fmaxf(v, __shfl_xor(v, 16));
    v = fmaxf(v, __shfl_xor(v, 8));  v = fmaxf(v, __shfl_xor(v, 4));
    v = fmaxf(v, __shfl_xor(v, 2));  v = fmaxf(v, __shfl_xor(v, 1));
    return v;
}
__device__ __forceinline__ void gload_lds16(const void* g, void* l) {
    __builtin_amdgcn_global_load_lds(
        (const __attribute__((address_space(1))) void*)g,
        (__attribute__((address_space(3))) void*)l, 16, 0, 0);
}

// ---------------- shared 128x128 MFMA tile (used by gemm_setup + vocab extras) ----------------
__device__ __forceinline__ void tile128(const u16* __restrict__ A, const u16* __restrict__ Bw,
                                        float* __restrict__ C, int m0, int n0, int Mlim, int Nlim,
                                        u16* As, u16* Bs, int tid) {
    const int wid = tid >> 6, lane = tid & 63;
    const int wr = wid >> 1, wc = wid & 1;
    f32x4 acc[4][4] = {};
    const int lcol = ((lane & 7) ^ ((lane >> 3) & 7)) * 8;
    const int lr = lane & 15, lg = lane >> 4, lx = lane & 7;
    const int sA0 = (lg ^ lx) * 8, sA1 = ((4 + lg) ^ lx) * 8;
    const u16* Ag = A + (size_t)(m0 + wid * 32 + (lane >> 3)) * KP_ + lcol;
    const u16* Bg = Bw + (size_t)(n0 + wid * 32 + (lane >> 3)) * KP_ + lcol;

    for (int kt = 0; kt < 7; ++kt) {
        const int k0 = kt * 64;
        #pragma unroll
        for (int is = 0; is < 4; ++is) {
            gload_lds16(Ag + (size_t)is * 8 * KP_ + k0, &As[(wid * 32 + is * 8) * 64]);
            gload_lds16(Bg + (size_t)is * 8 * KP_ + k0, &Bs[(wid * 32 + is * 8) * 64]);
        }
        __syncthreads();
        short8 af[4][2], bfr[4][2];
        #pragma unroll
        for (int i = 0; i < 4; ++i) {
            int ra = (wr * 64 + i * 16 + lr) * 64;
            af[i][0] = *reinterpret_cast<const short8*>(&As[ra + sA0]);
            af[i][1] = *reinterpret_cast<const short8*>(&As[ra + sA1]);
            int rb = (wc * 64 + i * 16 + lr) * 64;
            bfr[i][0] = *reinterpret_cast<const short8*>(&Bs[rb + sA0]);
            bfr[i][1] = *reinterpret_cast<const short8*>(&Bs[rb + sA1]);
        }
        #pragma unroll
        for (int h = 0; h < 2; ++h)
            #pragma unroll
            for (int i = 0; i < 4; ++i)
                #pragma unroll
                for (int j = 0; j < 4; ++j)
                    acc[i][j] = __builtin_amdgcn_mfma_f32_16x16x32_bf16(
                        af[i][h], bfr[j][h], acc[i][j], 0, 0, 0);
        __syncthreads();
    }
    const int m_base = m0 + wr * 64 + lg * 4;
    const int n_base = n0 + wc * 64 + lr;
    #pragma unroll
    for (int i = 0; i < 4; ++i)
        #pragma unroll
        for (int r = 0; r < 4; ++r) {
            int m = m_base + i * 16 + r;
            if (m >= Mlim) continue;
            #pragma unroll
            for (int j = 0; j < 4; ++j) {
                int n = n_base + j * 16;
                if (n < Nlim) C[(size_t)m * Nlim + n] = acc[i][j][r];
            }
        }
}

// ---------------- merged prep: h0 init + weight conv + x_all ----------------
__global__ void prep_all(const float* __restrict__ eh, const float* __restrict__ embW,
                         const float* __restrict__ Wih, const float* __restrict__ Whh,
                         const float* __restrict__ sembW, const int* __restrict__ tb,
                         const int* __restrict__ dom, const int* __restrict__ sli,
                         float* __restrict__ hid, u16* __restrict__ Ab,
                         u16* __restrict__ Bb, u16* __restrict__ Wihb, u16* __restrict__ Whhb,
                         float* __restrict__ x_all, u16* __restrict__ Xb_all) {
    const int R0 = MP_ * KP_;
    const int CB = NP_ * (KP_ / 8), CG = NG_ * (KP_ / 8);
    const int R1 = R0 + CB + 2 * CG;
    const int R2 = R1 + MA_ * (KP_ / 8);
    int i = blockIdx.x * 256 + threadIdx.x;
    if (i < R0) {
        int row = i / KP_, d = i - row * KP_;
        u16 v = 0;
        if (row < BS_ && d < H_) {
            float h = eh[(row % B_) * H_ + d];
            hid[row * H_ + d] = h;
            v = f2bf(h);
        }
        Ab[i] = v;
    } else if (i < R1) {
        int j = i - R0;
        const float* src; u16* dst; int rows;
        if (j < CB) { src = embW; dst = Bb; rows = V_; }
        else if (j < CB + CG) { src = Wih; dst = Wihb; rows = 3 * H_; j -= CB; }
        else { src = Whh; dst = Whhb; rows = 3 * H_; j -= CB + CG; }
        int row = j / (KP_ / 8), c8 = (j - row * (KP_ / 8)) * 8;
        short8 o = {};
        if (row < rows && c8 < H_) {
            const float4* s = reinterpret_cast<const float4*>(src + (size_t)row * H_ + c8);
            float4 a = s[0], b = s[1];
            o[0] = (short)f2bf(a.x); o[1] = (short)f2bf(a.y);
            o[2] = (short)f2bf(a.z); o[3] = (short)f2bf(a.w);
            o[4] = (short)f2bf(b.x); o[5] = (short)f2bf(b.y);
            o[6] = (short)f2bf(b.z); o[7] = (short)f2bf(b.w);
        }
        *reinterpret_cast<short8*>(dst + (size_t)row * KP_ + c8) = o;
    } else if (i < R2) {
        int j = i - R1;
        int row = j / (KP_ / 8), c8 = (j - row * (KP_ / 8)) * 8;
        int t = row / BS_, r = row - t * BS_;
        int batch = r % B_, slot = r / B_;
        short8 o = {};
        if (c8 < H_) {
            float4 a, b;
            if (t == 0) {
                const float4* s0 = reinterpret_cast<const float4*>(sembW + dom[slot] * H_ + c8);
                const float4* s1 = reinterpret_cast<const float4*>(sembW + sli[slot] * H_ + c8);
                float4 x0 = s0[0], x1 = s0[1], y0 = s1[0], y1 = s1[1];
                a = make_float4(x0.x + y0.x, x0.y + y0.y, x0.z + y0.z, x0.w + y0.w);
                b = make_float4(x1.x + y1.x, x1.y + y1.y, x1.z + y1.z, x1.w + y1.w);
            } else {
                int tok = tb[(batch * NS_ + slot) * T_ + (t - 1)];
                const float4* s = reinterpret_cast<const float4*>(embW + (size_t)tok * H_ + c8);
                a = s[0]; b = s[1];
            }
            o[0] = (short)f2bf(a.x); o[1] = (short)f2bf(a.y);
            o[2] = (short)f2bf(a.z); o[3] = (short)f2bf(a.w);
            o[4] = (short)f2bf(b.x); o[5] = (short)f2bf(b.y);
            o[6] = (short)f2bf(b.z); o[7] = (short)f2bf(b.w);
            *reinterpret_cast<float4*>(x_all + (size_t)row * H_ + c8) = a;
            *reinterpret_cast<float4*>(x_all + (size_t)row * H_ + c8 + 4) = b;
        }
        *reinterpret_cast<short8*>(Xb_all + (size_t)row * KP_ + c8) = o;
    }
}

// ---------------- minimal setup GEMM: gx m-tiles 0-3 (step-0 rows) + gh(0) ----------------
__global__ __launch_bounds__(256)
void gemm_setup(const u16* __restrict__ Xb_all, const u16* __restrict__ Abuf,
                const u16* __restrict__ Wihb, const u16* __restrict__ Whhb,
                float* __restrict__ gx_all, float* __restrict__ gh) {
    __shared__ u16 As[128 * 64];
    __shared__ u16 Bs[128 * 64];
    const int tid = threadIdx.x;
    const bool mainp = blockIdx.y < 4;
    const int m0 = (mainp ? blockIdx.y : blockIdx.y - 4) * 128;
    const int n0 = blockIdx.x * 128;
    if (mainp)
        tile128(Xb_all, Wihb, gx_all, m0, n0, MA_, 3 * H_, As, Bs, tid);
    else
        tile128(Abuf, Whhb, gh, m0, n0, BS_, 3 * H_, As, Bs, tid);
}

// ---------------- vocab (exp->pb + psum) + gh(t+1) + [t=0: gx tiles 4..29] ----------------
__global__ __launch_bounds__(256, 2)
void vocab_gh(const u16* __restrict__ A, const u16* __restrict__ Bb,
              const u16* __restrict__ Whhb, u16* __restrict__ pb,
              float* __restrict__ psum, float* __restrict__ gh,
              const u16* __restrict__ Xb_all, const u16* __restrict__ Wihb,
              float* __restrict__ gx_all) {
    __shared__ u16 As[256 * 64];      // 32 KB
    __shared__ u16 Bs[2][128 * 64];   // 2 x 16 KB
    __shared__ float sred[2][256];
    const int bid = blockIdx.x;
    const int tid = threadIdx.x;

    if (bid >= 412) {                 // t=0 only: gx tiles for steps 1..7
        const int e = bid - 412;      // 0..259
        const int mt = 4 + e / 10, nt = e % 10;
        tile128(Xb_all, Wihb, gx_all, mt * 128, nt * 128, MA_, 3 * H_,
                As, (u16*)&Bs[0][0], tid);
        return;
    }

    const int xcd = bid & 7, idx = bid >> 3;
    const int lin = (xcd < 4) ? (xcd * 52 + idx) : (208 + (xcd - 4) * 51 + idx);
    const int ntall = lin >> 1, mt = lin & 1;
    const bool isv = (ntall < NVT_);
    const int n0 = (isv ? ntall : ntall - NVT_) * 128;
    const int m0 = mt * 256;
    const u16* Bsrc = isv ? Bb : Whhb;

    const int wid = tid >> 6, lane = tid & 63;
    const int wr = wid >> 1, wc = wid & 1;
    f32x4 acc[8][4] = {};
    const int lcol = ((lane & 7) ^ ((lane >> 3) & 7)) * 8;
    const int lr = lane & 15, lg = lane >> 4, lx = lane & 7;
    const int sA0 = (lg ^ lx) * 8, sA1 = ((4 + lg) ^ lx) * 8;
    const u16* Ag = A + (size_t)(m0 + wid * 64 + (lane >> 3)) * KP_ + lcol;
    const u16* Bg = Bsrc + (size_t)(n0 + wid * 32 + (lane >> 3)) * KP_ + lcol;

    #pragma unroll
    for (int is = 0; is < 4; ++is)
        gload_lds16(Bg + (size_t)is * 8 * KP_, &Bs[0][(wid * 32 + is * 8) * 64]);

    for (int kt = 0; kt < 7; ++kt) {
        const int k0 = kt * 64, cur = kt & 1;
        #pragma unroll
        for (int is = 0; is < 8; ++is)
            gload_lds16(Ag + (size_t)is * 8 * KP_ + k0, &As[(wid * 64 + is * 8) * 64]);
        if (kt < 6) {
            #pragma unroll
            for (int is = 0; is < 4; ++is)
                gload_lds16(Bg + (size_t)is * 8 * KP_ + k0 + 64,
                            &Bs[cur ^ 1][(wid * 32 + is * 8) * 64]);
            asm volatile("s_waitcnt vmcnt(4)" ::: "memory");
        } else {
            asm volatile("s_waitcnt vmcnt(0)" ::: "memory");
        }
        __builtin_amdgcn_sched_barrier(0);
        __builtin_amdgcn_s_barrier();
        const u16* Bsl = Bs[cur];
        #pragma unroll
        for (int h = 0; h < 2; ++h) {
            const int sA = h ? sA1 : sA0;
            short8 af[8], bf[4];
            #pragma unroll
            for (int i = 0; i < 8; ++i)
                af[i] = *reinterpret_cast<const short8*>(&As[(wr * 128 + i * 16 + lr) * 64 + sA]);
            #pragma unroll
            for (int j = 0; j < 4; ++j)
                bf[j] = *reinterpret_cast<const short8*>(&Bsl[(wc * 64 + j * 16 + lr) * 64 + sA]);
            #pragma unroll
            for (int i = 0; i < 8; ++i)
                #pragma unroll
                for (int j = 0; j < 4; ++j)
                    acc[i][j] = __builtin_amdgcn_mfma_f32_16x16x32_bf16(
                        af[i], bf[j], acc[i][j], 0, 0, 0);
        }
        __builtin_amdgcn_s_barrier();
    }

    const int m_base = m0 + wr * 128 + lg * 4;
    const int n_base = n0 + wc * 64 + lr;
    if (isv) {
        #pragma unroll
        for (int i = 0; i < 8; ++i) {
            #pragma unroll
            for (int r = 0; r < 4; ++r) {
                int m = m_base + i * 16 + r;
                float js = 0.f;
                #pragma unroll
                for (int j = 0; j < 4; ++j) {
                    int n = n_base + j * 16;
                    float e = __expf(acc[i][j][r]);
                    if (m < BS_ && n < V_) {
                        pb[(size_t)m * V_ + n] = f2bf(e);
                        js += e;
                    }
                }
                js += __shfl_xor(js, 1);
                js += __shfl_xor(js, 2);
                js += __shfl_xor(js, 4);
                js += __shfl_xor(js, 8);
                if ((lane & 15) == 0) sred[wc][m - m0] = js;
            }
        }
        __syncthreads();
        {
            int m = m0 + tid;
            psum[(size_t)m * PSL_ + ntall] = sred[0][tid] + sred[1][tid];
        }
    } else {
        #pragma unroll
        for (int i = 0; i < 8; ++i)
            #pragma unroll
            for (int r = 0; r < 4; ++r) {
                int m = m_base + i * 16 + r;
                if (m >= BS_) continue;
                #pragma unroll
                for (int j = 0; j < 4; ++j) {
                    int n = n_base + j * 16;
                    if (n < 3 * H_) gh[(size_t)m * 3 * H_ + n] = acc[i][j][r];
                }
            }
    }
}

// ---------------- attn (even lin) + finalize t-1 (odd lin), one dispatch ----------------
__global__ __launch_bounds__(256)
void attn_fin(const float* __restrict__ gx_all, const float* __restrict__ gh,
              const float* __restrict__ bih, const float* __restrict__ bhh,
              float* __restrict__ hid, u16* __restrict__ Ab,
              const float* __restrict__ x_all,
              const float* __restrict__ enc, const int* __restrict__ story,
              const float* __restrict__ Wr, const float* __restrict__ Wrb,
              const float* __restrict__ Wg, const float* __restrict__ Wgb,
              float* __restrict__ prob_cur, float* __restrict__ sw_cur,
              float* __restrict__ gate_out,
              float* __restrict__ out, const u16* __restrict__ pb,
              const float* __restrict__ psum, const float* __restrict__ sw_prev,
              const float* __restrict__ prob_prev, int t) {
    const int bid = blockIdx.x;                    // 960 = 8*120
    const int lin = (bid & 7) * 120 + (bid >> 3);
    const int work = lin >> 1, kind = lin & 1;
    const int tid = threadIdx.x, w = tid >> 6, l = tid & 63;
    __shared__ __align__(16) float hs[H_];
    __shared__ __align__(16) float xs[H_];
    __shared__ __align__(16) float cs[H_];
    __shared__ __align__(16) float cpart[4][H_];
    __shared__ float sc[S_];
    __shared__ float red[16];

    if (kind == 1) {
        if (t == 0) return;
        const int row = work, batch = row % B_;
        float rs = (tid < NVT_) ? psum[(size_t)row * PSL_ + tid] : 0.f;
        rs = wred_sum(rs);
        if (l == 0) red[w] = rs;
        __syncthreads();
        float denom = red[0] + red[1] + red[2] + red[3];
        float swv = sw_prev[row];
        float scl = swv / denom;
        const u16* ps = pb + (size_t)row * V_;
        float* p = out + ((size_t)row * T_ + (t - 1)) * V_;
        for (int v = tid * 8; v < V_; v += 256 * 8) {
            short8 in = *reinterpret_cast<const short8*>(ps + v);
            float4 o0, o1;
            o0.x = bf2f((u16)in[0]) * scl; o0.y = bf2f((u16)in[1]) * scl;
            o0.z = bf2f((u16)in[2]) * scl; o0.w = bf2f((u16)in[3]) * scl;
            o1.x = bf2f((u16)in[4]) * scl; o1.y = bf2f((u16)in[5]) * scl;
            o1.z = bf2f((u16)in[6]) * scl; o1.w = bf2f((u16)in[7]) * scl;
            *reinterpret_cast<float4*>(p + v) = o0;
            *reinterpret_cast<float4*>(p + v + 4) = o1;
        }
        __syncthreads();
        float om = 1.f - swv;
        for (int s = tid; s < S_; s += 256) {
            int tok = story[batch * S_ + s];
            atomicAdd(p + tok, om * prob_prev[(size_t)row * S_ + s]);
        }
        return;
    }

    const int batch = work / 30, slot = work - batch * 30;
    const int row = slot * B_ + batch;

    const float* gxr = gx_all + ((size_t)t * BS_ + row) * 3 * H_;
    const float* ghr = gh + (size_t)row * 3 * H_;
    const float* xr  = x_all + ((size_t)t * BS_ + row) * H_;
    for (int d = tid; d < H_; d += 256) {
        float r = sigm(gxr[d] + bih[d] + ghr[d] + bhh[d]);
        float z = sigm(gxr[H_ + d] + bih[H_ + d] + ghr[H_ + d] + bhh[H_ + d]);
        float n = ftanh(gxr[2 * H_ + d] + bih[2 * H_ + d] + r * (ghr[2 * H_ + d] + bhh[2 * H_ + d]));
        float h = (1.f - z) * n + z * hid[(size_t)row * H_ + d];
        hs[d] = h;
        hid[(size_t)row * H_ + d] = h;
        Ab[(size_t)row * KP_ + d] = f2bf(h);
        xs[d] = xr[d];
    }
    __syncthreads();

    const float* encb = enc + (size_t)batch * S_ * H_;
    {
        float4 hv1 = *reinterpret_cast<const float4*>(&hs[l * 4]);
        float4 hv2 = make_float4(0.f, 0.f, 0.f, 0.f);
        if (l < 36) hv2 = *reinterpret_cast<const float4*>(&hs[256 + l * 4]);
        for (int k = 0; k < 50; k += 2) {
            int s0 = w * 50 + k;
            const float4* e0 = reinterpret_cast<const float4*>(encb + (size_t)s0 * H_);
            const float4* e1 = reinterpret_cast<const float4*>(encb + (size_t)(s0 + 1) * H_);
            float4 ev0 = e0[l], ev1 = e1[l];
            float p0 = ev0.x * hv1.x + ev0.y * hv1.y + ev0.z * hv1.z + ev0.w * hv1.w;
            float p1 = ev1.x * hv1.x + ev1.y * hv1.y + ev1.z * hv1.z + ev1.w * hv1.w;
            if (l < 36) {
                float4 f0 = e0[64 + l], f1 = e1[64 + l];
                p0 += f0.x * hv2.x + f0.y * hv2.y + f0.z * hv2.z + f0.w * hv2.w;
                p1 += f1.x * hv2.x + f1.y * hv2.y + f1.z * hv2.z + f1.w * hv2.w;
            }
            p0 = wred_sum(p0);
            p1 = wred_sum(p1);
            if (l == 0) {
                sc[s0]     = (story[batch * S_ + s0] == 0)     ? -1e30f : p0;
                sc[s0 + 1] = (story[batch * S_ + s0 + 1] == 0) ? -1e30f : p1;
            }
        }
    }
    __syncthreads();

    float v = (tid < S_) ? sc[tid] : -1e30f;
    float wm = wred_max(v);
    if (l == 0) red[w] = wm;
    __syncthreads();
    float mx = fmaxf(fmaxf(red[0], red[1]), fmaxf(red[2], red[3]));
    float e = (tid < S_) ? __expf(v - mx) : 0.f;
    float wsum = wred_sum(e);
    if (l == 0) red[4 + w] = wsum;
    __syncthreads();
    float inv = 1.f / (red[4] + red[5] + red[6] + red[7]);
    if (tid < S_) {
        float pv = e * inv;
        sc[tid] = pv;
        prob_cur[(size_t)row * S_ + tid] = pv;
    }
    __syncthreads();

    {
        const int s0 = w * 50;
        for (int d = l; d < H_; d += 64) {
            float a0 = 0.f, a1 = 0.f;
            for (int k = 0; k < 50; k += 2) {
                a0 += sc[s0 + k]     * encb[(size_t)(s0 + k) * H_ + d];
                a1 += sc[s0 + k + 1] * encb[(size_t)(s0 + k + 1) * H_ + d];
            }
            cpart[w][d] = a0 + a1;
        }
    }
    __syncthreads();
    for (int d = tid; d < H_; d += 256)
        cs[d] = cpart[0][d] + cpart[1][d] + cpart[2][d] + cpart[3][d];
    __syncthreads();

    float part = 0.f;
    for (int i = tid; i < 3 * H_; i += 256) {
        float xv = (i < H_) ? hs[i] : (i < 2 * H_) ? cs[i - H_] : xs[i - 2 * H_];
        part += xv * Wr[i];
    }
    part = wred_sum(part);
    if (l == 0) red[8 + w] = part;
    __syncthreads();
    if (tid == 0)
        sw_cur[row] = sigm(red[8] + red[9] + red[10] + red[11] + Wrb[0]);

    if (t == 0 && tid < NB_) {
        float acc = 0.f;
        for (int d = 0; d < H_; ++d) acc += cs[d] * Wg[tid * H_ + d];
        gate_out[(size_t)row * NB_ + tid] = acc + Wgb[tid];
    }
}

// ---------------- final-step finalize ----------------
__global__ __launch_bounds__(256)
void scale_scatter(float* __restrict__ out, const u16* __restrict__ pb,
                   const float* __restrict__ psum, const float* __restrict__ sw,
                   const float* __restrict__ prob, const int* __restrict__ story) {
    const int row = blockIdx.x;
    const int tid = threadIdx.x, w = tid >> 6, l = tid & 63;
    __shared__ float red[4];
    float rs = (tid < NVT_) ? psum[(size_t)row * PSL_ + tid] : 0.f;
    rs = wred_sum(rs);
    if (l == 0) red[w] = rs;
    __syncthreads();
    float denom = red[0] + red[1] + red[2] + red[3];
    float swv = sw[row];
    float scl = swv / denom;
    const u16* ps = pb + (size_t)row * V_;
    float* p = out + ((size_t)row * T_ + (T_ - 1)) * V_;
    for (int v = tid * 8; v < V_; v += 256 * 8) {
        short8 in = *reinterpret_cast<const short8*>(ps + v);
        float4 o0, o1;
        o0.x = bf2f((u16)in[0]) * scl; o0.y = bf2f((u16)in[1]) * scl;
        o0.z = bf2f((u16)in[2]) * scl; o0.w = bf2f((u16)in[3]) * scl;
        o1.x = bf2f((u16)in[4]) * scl; o1.y = bf2f((u16)in[5]) * scl;
        o1.z = bf2f((u16)in[6]) * scl; o1.w = bf2f((u16)in[7]) * scl;
        *reinterpret_cast<float4*>(p + v) = o0;
        *reinterpret_cast<float4*>(p + v + 4) = o1;
    }
    __syncthreads();
    const int batch = row % B_;
    float om = 1.f - swv;
    for (int s = tid; s < S_; s += 256) {
        int tok = story[batch * S_ + s];
        atomicAdd(p + tok, om * prob[(size_t)row * S_ + s]);
    }
}

extern "C" void kernel_launch(void* const* d_in, const int* in_sizes, int n_in,
                              void* d_out, int out_size, void* d_ws, size_t ws_size,
                              hipStream_t stream) {
    const float* eh    = (const float*)d_in[0];
    const float* enc   = (const float*)d_in[1];
    const int*   story = (const int*)d_in[2];
    const int*   tb    = (const int*)d_in[3];
    const int*   dom   = (const int*)d_in[4];
    const int*   sli   = (const int*)d_in[5];
    const float* embW  = (const float*)d_in[6];
    const float* sembW = (const float*)d_in[7];
    const float* Wih   = (const float*)d_in[8];
    const float* Whh   = (const float*)d_in[9];
    const float* bih   = (const float*)d_in[10];
    const float* bhh   = (const float*)d_in[11];
    const float* Wr    = (const float*)d_in[12];
    const float* Wrb   = (const float*)d_in[13];
    const float* Wg    = (const float*)d_in[14];
    const float* Wgb   = (const float*)d_in[15];

    float* out = (float*)d_out;
    float* ws  = (float*)d_ws;

    float* gx_all = ws;
    float* gh     = gx_all + (size_t)MA_ * 3 * H_;
    float* hid    = gh + (size_t)BS_ * 3 * H_;
    float* x_all  = hid + (size_t)BS_ * H_;
    float* prob2  = x_all + (size_t)MA_ * H_;
    float* sw2    = prob2 + 2 * BS_ * S_;
    float* psum   = sw2 + 2 * BS_;
    u16* Ab     = (u16*)(psum + (size_t)MP_ * PSL_);
    u16* Xb_all = Ab + (size_t)MP_ * KP_;
    u16* Wihb   = Xb_all + (size_t)MA_ * KP_;
    u16* Whhb   = Wihb + (size_t)NG_ * KP_;
    u16* Bb     = Whhb + (size_t)NG_ * KP_;
    u16* pb     = Bb + (size_t)NP_ * KP_;
    size_t need = (size_t)((char*)(pb + (size_t)BS_ * V_) - (char*)ws);
    if (ws_size < need) return;

    float* gate_out = out + (size_t)NS_ * B_ * T_ * V_;

    {
        const int R2 = MP_ * KP_ + (NP_ + 2 * NG_) * (KP_ / 8) + MA_ * (KP_ / 8);
        prep_all<<<(R2 + 255) / 256, 256, 0, stream>>>(eh, embW, Wih, Whh, sembW, tb, dom, sli,
                                                       hid, Ab, Bb, Wihb, Whhb, x_all, Xb_all);
    }
    // minimal setup: gx m-tiles 0-3 (covers all of step 0's rows) + gh(0)
    gemm_setup<<<dim3(NG_ / 128, 8), 256, 0, stream>>>(Xb_all, Ab, Wihb, Whhb, gx_all, gh);

    for (int t = 0; t < T_; ++t) {
        const int cur = t & 1, prev = cur ^ 1;
        attn_fin<<<960, 256, 0, stream>>>(gx_all, gh, bih, bhh, hid, Ab, x_all,
                                          enc, story, Wr, Wrb, Wg, Wgb,
                                          prob2 + cur * BS_ * S_, sw2 + cur * BS_,
                                          gate_out, out, pb, psum,
                                          sw2 + prev * BS_, prob2 + prev * BS_ * S_, t);
        // t=0: +260 extra blocks compute gx for steps 1..7 (needed first by attn(1))
        vocab_gh<<<(t == 0 ? 672 : 412), 256, 0, stream>>>(Ab, Bb, Whhb, pb, psum, gh,
                                                           Xb_all, Wihb, gx_all);
    }
    {
        const int last = (T_ - 1) & 1;
        scale_scatter<<<BS_, 256, 0, stream>>>(out, pb, psum, sw2 + last * BS_,
                                               prob2 + last * BS_ * S_, story);
    }
}

// Round 15
// 758.530 us; speedup vs baseline: 1.0239x; 1.0239x over previous
//
#include <hip/hip_runtime.h>
#include <math.h>

#define B_   16
#define S_   200
#define H_   400
#define V_   25000
#define T_   8
#define NS_  30
#define NB_  3
#define BS_  480   // NS_*B_

#define KP_  448   // K padded (7 tiles of 64)
#define MP_  512
#define NP_  25088 // vocab N padded (196 tiles of 128)
#define NG_  1280  // gates N padded (10 tiles of 128)
#define MA_  3840  // T_*BS_
#define NVT_ (NP_/128)   // 196
#define PSL_ 200

typedef unsigned short u16;
typedef __attribute__((ext_vector_type(4))) float f32x4;
typedef __attribute__((ext_vector_type(8))) short short8;
typedef __attribute__((ext_vector_type(4))) short short4v;

__device__ __forceinline__ u16 f2bf(float f) {
    unsigned u = __float_as_uint(f);
    u += 0x7FFFu + ((u >> 16) & 1u);
    return (u16)(u >> 16);
}
__device__ __forceinline__ float bf2f(u16 v) {
    return __uint_as_float(((unsigned)v) << 16);
}
__device__ __forceinline__ float sigm(float x) {
    return 1.f / (1.f + __expf(-x));
}
__device__ __forceinline__ float ftanh(float x) {
    float e2 = __expf(2.f * x);
    return 1.f - 2.f / (e2 + 1.f);
}
__device__ __forceinline__ float wred_sum(float v) {
    v += __shfl_xor(v, 32); v += __shfl_xor(v, 16); v += __shfl_xor(v, 8);
    v += __shfl_xor(v, 4);  v += __shfl_xor(v, 2);  v += __shfl_xor(v, 1);
    return v;
}
__device__ __forceinline__ float wred_max(float v) {
    v = fmaxf(v, __shfl_xor(v, 32)); v = fmaxf(v, __shfl_xor(v, 16));
    v = fmaxf(v, __shfl_xor(v, 8));  v = fmaxf(v, __shfl_xor(v, 4));
    v = fmaxf(v, __shfl_xor(v, 2));  v = fmaxf(v, __shfl_xor(v, 1));
    return v;
}
__device__ __forceinline__ void gload_lds16(const void* g, void* l) {
    __builtin_amdgcn_global_load_lds(
        (const __attribute__((address_space(1))) void*)g,
        (__attribute__((address_space(3))) void*)l, 16, 0, 0);
}

// ---------------- shared 128x128 MFMA tile (gemm_setup) ----------------
__device__ __forceinline__ void tile128(const u16* __restrict__ A, const u16* __restrict__ Bw,
                                        float* __restrict__ C, int m0, int n0, int Mlim, int Nlim,
                                        u16* As, u16* Bs, int tid) {
    const int wid = tid >> 6, lane = tid & 63;
    const int wr = wid >> 1, wc = wid & 1;
    f32x4 acc[4][4] = {};
    const int lcol = ((lane & 7) ^ ((lane >> 3) & 7)) * 8;
    const int lr = lane & 15, lg = lane >> 4, lx = lane & 7;
    const int sA0 = (lg ^ lx) * 8, sA1 = ((4 + lg) ^ lx) * 8;
    const u16* Ag = A + (size_t)(m0 + wid * 32 + (lane >> 3)) * KP_ + lcol;
    const u16* Bg = Bw + (size_t)(n0 + wid * 32 + (lane >> 3)) * KP_ + lcol;

    for (int kt = 0; kt < 7; ++kt) {
        const int k0 = kt * 64;
        #pragma unroll
        for (int is = 0; is < 4; ++is) {
            gload_lds16(Ag + (size_t)is * 8 * KP_ + k0, &As[(wid * 32 + is * 8) * 64]);
            gload_lds16(Bg + (size_t)is * 8 * KP_ + k0, &Bs[(wid * 32 + is * 8) * 64]);
        }
        __syncthreads();
        short8 af[4][2], bfr[4][2];
        #pragma unroll
        for (int i = 0; i < 4; ++i) {
            int ra = (wr * 64 + i * 16 + lr) * 64;
            af[i][0] = *reinterpret_cast<const short8*>(&As[ra + sA0]);
            af[i][1] = *reinterpret_cast<const short8*>(&As[ra + sA1]);
            int rb = (wc * 64 + i * 16 + lr) * 64;
            bfr[i][0] = *reinterpret_cast<const short8*>(&Bs[rb + sA0]);
            bfr[i][1] = *reinterpret_cast<const short8*>(&Bs[rb + sA1]);
        }
        #pragma unroll
        for (int h = 0; h < 2; ++h)
            #pragma unroll
            for (int i = 0; i < 4; ++i)
                #pragma unroll
                for (int j = 0; j < 4; ++j)
                    acc[i][j] = __builtin_amdgcn_mfma_f32_16x16x32_bf16(
                        af[i][h], bfr[j][h], acc[i][j], 0, 0, 0);
        __syncthreads();
    }
    const int m_base = m0 + wr * 64 + lg * 4;
    const int n_base = n0 + wc * 64 + lr;
    #pragma unroll
    for (int i = 0; i < 4; ++i)
        #pragma unroll
        for (int r = 0; r < 4; ++r) {
            int m = m_base + i * 16 + r;
            if (m >= Mlim) continue;
            #pragma unroll
            for (int j = 0; j < 4; ++j) {
                int n = n_base + j * 16;
                if (n < Nlim) C[(size_t)m * Nlim + n] = acc[i][j][r];
            }
        }
}

// ---------------- merged prep: h0 init + weight conv + x_all ----------------
__global__ void prep_all(const float* __restrict__ eh, const float* __restrict__ embW,
                         const float* __restrict__ Wih, const float* __restrict__ Whh,
                         const float* __restrict__ sembW, const int* __restrict__ tb,
                         const int* __restrict__ dom, const int* __restrict__ sli,
                         float* __restrict__ hid, u16* __restrict__ Ab,
                         u16* __restrict__ Bb, u16* __restrict__ Wihb, u16* __restrict__ Whhb,
                         float* __restrict__ x_all, u16* __restrict__ Xb_all) {
    const int R0 = MP_ * KP_;
    const int CB = NP_ * (KP_ / 8), CG = NG_ * (KP_ / 8);
    const int R1 = R0 + CB + 2 * CG;
    const int R2 = R1 + MA_ * (KP_ / 8);
    int i = blockIdx.x * 256 + threadIdx.x;
    if (i < R0) {
        int row = i / KP_, d = i - row * KP_;
        u16 v = 0;
        if (row < BS_ && d < H_) {
            float h = eh[(row % B_) * H_ + d];
            hid[row * H_ + d] = h;
            v = f2bf(h);
        }
        Ab[i] = v;
    } else if (i < R1) {
        int j = i - R0;
        const float* src; u16* dst; int rows;
        if (j < CB) { src = embW; dst = Bb; rows = V_; }
        else if (j < CB + CG) { src = Wih; dst = Wihb; rows = 3 * H_; j -= CB; }
        else { src = Whh; dst = Whhb; rows = 3 * H_; j -= CB + CG; }
        int row = j / (KP_ / 8), c8 = (j - row * (KP_ / 8)) * 8;
        short8 o = {};
        if (row < rows && c8 < H_) {
            const float4* s = reinterpret_cast<const float4*>(src + (size_t)row * H_ + c8);
            float4 a = s[0], b = s[1];
            o[0] = (short)f2bf(a.x); o[1] = (short)f2bf(a.y);
            o[2] = (short)f2bf(a.z); o[3] = (short)f2bf(a.w);
            o[4] = (short)f2bf(b.x); o[5] = (short)f2bf(b.y);
            o[6] = (short)f2bf(b.z); o[7] = (short)f2bf(b.w);
        }
        *reinterpret_cast<short8*>(dst + (size_t)row * KP_ + c8) = o;
    } else if (i < R2) {
        int j = i - R1;
        int row = j / (KP_ / 8), c8 = (j - row * (KP_ / 8)) * 8;
        int t = row / BS_, r = row - t * BS_;
        int batch = r % B_, slot = r / B_;
        short8 o = {};
        if (c8 < H_) {
            float4 a, b;
            if (t == 0) {
                const float4* s0 = reinterpret_cast<const float4*>(sembW + dom[slot] * H_ + c8);
                const float4* s1 = reinterpret_cast<const float4*>(sembW + sli[slot] * H_ + c8);
                float4 x0 = s0[0], x1 = s0[1], y0 = s1[0], y1 = s1[1];
                a = make_float4(x0.x + y0.x, x0.y + y0.y, x0.z + y0.z, x0.w + y0.w);
                b = make_float4(x1.x + y1.x, x1.y + y1.y, x1.z + y1.z, x1.w + y1.w);
            } else {
                int tok = tb[(batch * NS_ + slot) * T_ + (t - 1)];
                const float4* s = reinterpret_cast<const float4*>(embW + (size_t)tok * H_ + c8);
                a = s[0]; b = s[1];
            }
            o[0] = (short)f2bf(a.x); o[1] = (short)f2bf(a.y);
            o[2] = (short)f2bf(a.z); o[3] = (short)f2bf(a.w);
            o[4] = (short)f2bf(b.x); o[5] = (short)f2bf(b.y);
            o[6] = (short)f2bf(b.z); o[7] = (short)f2bf(b.w);
            *reinterpret_cast<float4*>(x_all + (size_t)row * H_ + c8) = a;
            *reinterpret_cast<float4*>(x_all + (size_t)row * H_ + c8 + 4) = b;
        }
        *reinterpret_cast<short8*>(Xb_all + (size_t)row * KP_ + c8) = o;
    }
}

// ---------------- setup GEMMs: full gx_all (y<30) + gh(0) (y>=30) ----------------
__global__ __launch_bounds__(256)
void gemm_setup(const u16* __restrict__ Xb_all, const u16* __restrict__ Abuf,
                const u16* __restrict__ Wihb, const u16* __restrict__ Whhb,
                float* __restrict__ gx_all, float* __restrict__ gh) {
    __shared__ u16 As[128 * 64];
    __shared__ u16 Bs[128 * 64];
    const int tid = threadIdx.x;
    const bool mainp = blockIdx.y < (MA_ / 128);
    const int m0 = (mainp ? blockIdx.y : blockIdx.y - MA_ / 128) * 128;
    const int n0 = blockIdx.x * 128;
    if (mainp)
        tile128(Xb_all, Wihb, gx_all, m0, n0, MA_, 3 * H_, As, Bs, tid);
    else
        tile128(Abuf, Whhb, gh, m0, n0, BS_, 3 * H_, As, Bs, tid);
}

// ---------------- vocab (exp->pb + psum) + gh(t+1), 256x128 tile ----------------
// Epilogue stages the bf16 tile in LDS (reusing As/Bs) -> fully coalesced stores.
__global__ __launch_bounds__(256, 2)
void vocab_gh(const u16* __restrict__ A, const u16* __restrict__ Bb,
              const u16* __restrict__ Whhb, u16* __restrict__ pb,
              float* __restrict__ psum, float* __restrict__ gh) {
    __shared__ u16 SM[256 * 64 + 2 * 128 * 64];   // 64 KB: As | Bs0 | Bs1
    __shared__ float sred[2][256];
    u16* As  = SM;
    u16* Bs0 = SM + 256 * 64;
    u16* Bs1 = SM + 256 * 64 + 128 * 64;
    const int bid = blockIdx.x;       // 412 = 8 XCDs: 52,52,52,52,51,51,51,51
    const int tid = threadIdx.x;
    const int xcd = bid & 7, idx = bid >> 3;
    const int lin = (xcd < 4) ? (xcd * 52 + idx) : (208 + (xcd - 4) * 51 + idx);
    const int ntall = lin >> 1, mt = lin & 1;
    const bool isv = (ntall < NVT_);
    const int n0 = (isv ? ntall : ntall - NVT_) * 128;
    const int m0 = mt * 256;
    const u16* Bsrc = isv ? Bb : Whhb;

    const int wid = tid >> 6, lane = tid & 63;
    const int wr = wid >> 1, wc = wid & 1;
    f32x4 acc[8][4] = {};
    const int lcol = ((lane & 7) ^ ((lane >> 3) & 7)) * 8;
    const int lr = lane & 15, lg = lane >> 4, lx = lane & 7;
    const int sA0 = (lg ^ lx) * 8, sA1 = ((4 + lg) ^ lx) * 8;
    const u16* Ag = A + (size_t)(m0 + wid * 64 + (lane >> 3)) * KP_ + lcol;
    const u16* Bg = Bsrc + (size_t)(n0 + wid * 32 + (lane >> 3)) * KP_ + lcol;

    #pragma unroll
    for (int is = 0; is < 4; ++is)
        gload_lds16(Bg + (size_t)is * 8 * KP_, &Bs0[(wid * 32 + is * 8) * 64]);

    for (int kt = 0; kt < 7; ++kt) {
        const int k0 = kt * 64, cur = kt & 1;
        #pragma unroll
        for (int is = 0; is < 8; ++is)
            gload_lds16(Ag + (size_t)is * 8 * KP_ + k0, &As[(wid * 64 + is * 8) * 64]);
        if (kt < 6) {
            u16* Bnxt = cur ? Bs0 : Bs1;
            #pragma unroll
            for (int is = 0; is < 4; ++is)
                gload_lds16(Bg + (size_t)is * 8 * KP_ + k0 + 64,
                            &Bnxt[(wid * 32 + is * 8) * 64]);
            asm volatile("s_waitcnt vmcnt(4)" ::: "memory");
        } else {
            asm volatile("s_waitcnt vmcnt(0)" ::: "memory");
        }
        __builtin_amdgcn_sched_barrier(0);
        __builtin_amdgcn_s_barrier();
        const u16* Bsl = cur ? Bs1 : Bs0;
        #pragma unroll
        for (int h = 0; h < 2; ++h) {
            const int sA = h ? sA1 : sA0;
            short8 af[8], bf[4];
            #pragma unroll
            for (int i = 0; i < 8; ++i)
                af[i] = *reinterpret_cast<const short8*>(&As[(wr * 128 + i * 16 + lr) * 64 + sA]);
            #pragma unroll
            for (int j = 0; j < 4; ++j)
                bf[j] = *reinterpret_cast<const short8*>(&Bsl[(wc * 64 + j * 16 + lr) * 64 + sA]);
            #pragma unroll
            for (int i = 0; i < 8; ++i)
                #pragma unroll
                for (int j = 0; j < 4; ++j)
                    acc[i][j] = __builtin_amdgcn_mfma_f32_16x16x32_bf16(
                        af[i], bf[j], acc[i][j], 0, 0, 0);
        }
        __builtin_amdgcn_s_barrier();
    }

    if (isv) {
        // stage exp() results in LDS [256][128] bf16, accumulate row partials
        u16* pbs = SM;    // 64 KB, exactly 256*128 u16
        #pragma unroll
        for (int i = 0; i < 8; ++i) {
            #pragma unroll
            for (int r = 0; r < 4; ++r) {
                const int mloc = wr * 128 + i * 16 + lg * 4 + r;
                float js = 0.f;
                #pragma unroll
                for (int j = 0; j < 4; ++j) {
                    const int nloc = wc * 64 + j * 16 + lr;
                    float e = __expf(acc[i][j][r]);
                    pbs[mloc * 128 + nloc] = f2bf(e);
                    if (m0 + mloc < BS_ && n0 + nloc < V_) js += e;
                }
                js += __shfl_xor(js, 1);
                js += __shfl_xor(js, 2);
                js += __shfl_xor(js, 4);
                js += __shfl_xor(js, 8);
                if ((lane & 15) == 0) sred[wc][mloc] = js;
            }
        }
        __syncthreads();
        {
            int m = m0 + tid;
            psum[(size_t)m * PSL_ + ntall] = sred[0][tid] + sred[1][tid];
        }
        // coalesced copy-out: 4096 chunks of 16 B
        const int mmax = BS_ - m0;   // 480 or 224
        for (int c = tid; c < 256 * 16; c += 256) {
            const int mloc = c >> 4, c8 = (c & 15) * 8;
            if (mloc < mmax && n0 + c8 + 8 <= V_)
                *reinterpret_cast<short8*>(pb + (size_t)(m0 + mloc) * V_ + n0 + c8) =
                    *reinterpret_cast<const short8*>(pbs + mloc * 128 + c8);
        }
    } else {
        const int m_base = m0 + wr * 128 + lg * 4;
        const int n_base = n0 + wc * 64 + lr;
        #pragma unroll
        for (int i = 0; i < 8; ++i)
            #pragma unroll
            for (int r = 0; r < 4; ++r) {
                int m = m_base + i * 16 + r;
                if (m >= BS_) continue;
                #pragma unroll
                for (int j = 0; j < 4; ++j) {
                    int n = n_base + j * 16;
                    if (n < 3 * H_) gh[(size_t)m * 3 * H_ + n] = acc[i][j][r];
                }
            }
    }
}

// ---------------- attn (even lin) + finalize t-1 (odd lin), one dispatch ----------------
__global__ __launch_bounds__(256)
void attn_fin(const float* __restrict__ gx_all, const float* __restrict__ gh,
              const float* __restrict__ bih, const float* __restrict__ bhh,
              float* __restrict__ hid, u16* __restrict__ Ab,
              const float* __restrict__ x_all,
              const float* __restrict__ enc, const int* __restrict__ story,
              const float* __restrict__ Wr, const float* __restrict__ Wrb,
              const float* __restrict__ Wg, const float* __restrict__ Wgb,
              float* __restrict__ prob_cur, float* __restrict__ sw_cur,
              float* __restrict__ gate_out,
              float* __restrict__ out, const u16* __restrict__ pb,
              const float* __restrict__ psum, const float* __restrict__ sw_prev,
              const float* __restrict__ prob_prev, int t) {
    const int bid = blockIdx.x;                    // 960 = 8*120
    const int lin = (bid & 7) * 120 + (bid >> 3);
    const int work = lin >> 1, kind = lin & 1;
    const int tid = threadIdx.x, w = tid >> 6, l = tid & 63;
    __shared__ __align__(16) float hs[H_];
    __shared__ __align__(16) float xs[H_];
    __shared__ __align__(16) float cs[H_];
    __shared__ __align__(16) float cpart[4][H_];
    __shared__ float sc[S_];
    __shared__ float red[16];

    if (kind == 1) {
        if (t == 0) return;
        const int row = work, batch = row % B_;
        float rs = (tid < NVT_) ? psum[(size_t)row * PSL_ + tid] : 0.f;
        rs = wred_sum(rs);
        if (l == 0) red[w] = rs;
        __syncthreads();
        float denom = red[0] + red[1] + red[2] + red[3];
        float swv = sw_prev[row];
        float scl = swv / denom;
        const u16* ps = pb + (size_t)row * V_;
        float* p = out + ((size_t)row * T_ + (t - 1)) * V_;
        for (int v = tid * 4; v < V_; v += 1024) {      // dense float4 stores
            short4v in = *reinterpret_cast<const short4v*>(ps + v);
            float4 o;
            o.x = bf2f((u16)in[0]) * scl; o.y = bf2f((u16)in[1]) * scl;
            o.z = bf2f((u16)in[2]) * scl; o.w = bf2f((u16)in[3]) * scl;
            *reinterpret_cast<float4*>(p + v) = o;
        }
        __syncthreads();
        float om = 1.f - swv;
        for (int s = tid; s < S_; s += 256) {
            int tok = story[batch * S_ + s];
            atomicAdd(p + tok, om * prob_prev[(size_t)row * S_ + s]);
        }
        return;
    }

    const int batch = work / 30, slot = work - batch * 30;
    const int row = slot * B_ + batch;

    const float* gxr = gx_all + ((size_t)t * BS_ + row) * 3 * H_;
    const float* ghr = gh + (size_t)row * 3 * H_;
    const float* xr  = x_all + ((size_t)t * BS_ + row) * H_;
    for (int d = tid; d < H_; d += 256) {
        float r = sigm(gxr[d] + bih[d] + ghr[d] + bhh[d]);
        float z = sigm(gxr[H_ + d] + bih[H_ + d] + ghr[H_ + d] + bhh[H_ + d]);
        float n = ftanh(gxr[2 * H_ + d] + bih[2 * H_ + d] + r * (ghr[2 * H_ + d] + bhh[2 * H_ + d]));
        float h = (1.f - z) * n + z * hid[(size_t)row * H_ + d];
        hs[d] = h;
        hid[(size_t)row * H_ + d] = h;
        Ab[(size_t)row * KP_ + d] = f2bf(h);
        xs[d] = xr[d];
    }
    __syncthreads();

    const float* encb = enc + (size_t)batch * S_ * H_;
    {
        float4 hv1 = *reinterpret_cast<const float4*>(&hs[l * 4]);
        float4 hv2 = make_float4(0.f, 0.f, 0.f, 0.f);
        if (l < 36) hv2 = *reinterpret_cast<const float4*>(&hs[256 + l * 4]);
        for (int k = 0; k < 50; k += 2) {
            int s0 = w * 50 + k;
            const float4* e0 = reinterpret_cast<const float4*>(encb + (size_t)s0 * H_);
            const float4* e1 = reinterpret_cast<const float4*>(encb + (size_t)(s0 + 1) * H_);
            float4 ev0 = e0[l], ev1 = e1[l];
            float p0 = ev0.x * hv1.x + ev0.y * hv1.y + ev0.z * hv1.z + ev0.w * hv1.w;
            float p1 = ev1.x * hv1.x + ev1.y * hv1.y + ev1.z * hv1.z + ev1.w * hv1.w;
            if (l < 36) {
                float4 f0 = e0[64 + l], f1 = e1[64 + l];
                p0 += f0.x * hv2.x + f0.y * hv2.y + f0.z * hv2.z + f0.w * hv2.w;
                p1 += f1.x * hv2.x + f1.y * hv2.y + f1.z * hv2.z + f1.w * hv2.w;
            }
            p0 = wred_sum(p0);
            p1 = wred_sum(p1);
            if (l == 0) {
                sc[s0]     = (story[batch * S_ + s0] == 0)     ? -1e30f : p0;
                sc[s0 + 1] = (story[batch * S_ + s0 + 1] == 0) ? -1e30f : p1;
            }
        }
    }
    __syncthreads();

    float v = (tid < S_) ? sc[tid] : -1e30f;
    float wm = wred_max(v);
    if (l == 0) red[w] = wm;
    __syncthreads();
    float mx = fmaxf(fmaxf(red[0], red[1]), fmaxf(red[2], red[3]));
    float e = (tid < S_) ? __expf(v - mx) : 0.f;
    float wsum = wred_sum(e);
    if (l == 0) red[4 + w] = wsum;
    __syncthreads();
    float inv = 1.f / (red[4] + red[5] + red[6] + red[7]);
    if (tid < S_) {
        float pv = e * inv;
        sc[tid] = pv;
        prob_cur[(size_t)row * S_ + tid] = pv;
    }
    __syncthreads();

    {
        const int s0 = w * 50;
        for (int d = l; d < H_; d += 64) {
            float a0 = 0.f, a1 = 0.f;
            for (int k = 0; k < 50; k += 2) {
                a0 += sc[s0 + k]     * encb[(size_t)(s0 + k) * H_ + d];
                a1 += sc[s0 + k + 1] * encb[(size_t)(s0 + k + 1) * H_ + d];
            }
            cpart[w][d] = a0 + a1;
        }
    }
    __syncthreads();
    for (int d = tid; d < H_; d += 256)
        cs[d] = cpart[0][d] + cpart[1][d] + cpart[2][d] + cpart[3][d];
    __syncthreads();

    float part = 0.f;
    for (int i = tid; i < 3 * H_; i += 256) {
        float xv = (i < H_) ? hs[i] : (i < 2 * H_) ? cs[i - H_] : xs[i - 2 * H_];
        part += xv * Wr[i];
    }
    part = wred_sum(part);
    if (l == 0) red[8 + w] = part;
    __syncthreads();
    if (tid == 0)
        sw_cur[row] = sigm(red[8] + red[9] + red[10] + red[11] + Wrb[0]);

    if (t == 0 && tid < NB_) {
        float acc = 0.f;
        for (int d = 0; d < H_; ++d) acc += cs[d] * Wg[tid * H_ + d];
        gate_out[(size_t)row * NB_ + tid] = acc + Wgb[tid];
    }
}

// ---------------- final-step finalize ----------------
__global__ __launch_bounds__(256)
void scale_scatter(float* __restrict__ out, const u16* __restrict__ pb,
                   const float* __restrict__ psum, const float* __restrict__ sw,
                   const float* __restrict__ prob, const int* __restrict__ story) {
    const int row = blockIdx.x;
    const int tid = threadIdx.x, w = tid >> 6, l = tid & 63;
    __shared__ float red[4];
    float rs = (tid < NVT_) ? psum[(size_t)row * PSL_ + tid] : 0.f;
    rs = wred_sum(rs);
    if (l == 0) red[w] = rs;
    __syncthreads();
    float denom = red[0] + red[1] + red[2] + red[3];
    float swv = sw[row];
    float scl = swv / denom;
    const u16* ps = pb + (size_t)row * V_;
    float* p = out + ((size_t)row * T_ + (T_ - 1)) * V_;
    for (int v = tid * 4; v < V_; v += 1024) {
        short4v in = *reinterpret_cast<const short4v*>(ps + v);
        float4 o;
        o.x = bf2f((u16)in[0]) * scl; o.y = bf2f((u16)in[1]) * scl;
        o.z = bf2f((u16)in[2]) * scl; o.w = bf2f((u16)in[3]) * scl;
        *reinterpret_cast<float4*>(p + v) = o;
    }
    __syncthreads();
    const int batch = row % B_;
    float om = 1.f - swv;
    for (int s = tid; s < S_; s += 256) {
        int tok = story[batch * S_ + s];
        atomicAdd(p + tok, om * prob[(size_t)row * S_ + s]);
    }
}

extern "C" void kernel_launch(void* const* d_in, const int* in_sizes, int n_in,
                              void* d_out, int out_size, void* d_ws, size_t ws_size,
                              hipStream_t stream) {
    const float* eh    = (const float*)d_in[0];
    const float* enc   = (const float*)d_in[1];
    const int*   story = (const int*)d_in[2];
    const int*   tb    = (const int*)d_in[3];
    const int*   dom   = (const int*)d_in[4];
    const int*   sli   = (const int*)d_in[5];
    const float* embW  = (const float*)d_in[6];
    const float* sembW = (const float*)d_in[7];
    const float* Wih   = (const float*)d_in[8];
    const float* Whh   = (const float*)d_in[9];
    const float* bih   = (const float*)d_in[10];
    const float* bhh   = (const float*)d_in[11];
    const float* Wr    = (const float*)d_in[12];
    const float* Wrb   = (const float*)d_in[13];
    const float* Wg    = (const float*)d_in[14];
    const float* Wgb   = (const float*)d_in[15];

    float* out = (float*)d_out;
    float* ws  = (float*)d_ws;

    float* gx_all = ws;
    float* gh     = gx_all + (size_t)MA_ * 3 * H_;
    float* hid    = gh + (size_t)BS_ * 3 * H_;
    float* x_all  = hid + (size_t)BS_ * H_;
    float* prob2  = x_all + (size_t)MA_ * H_;
    float* sw2    = prob2 + 2 * BS_ * S_;
    float* psum   = sw2 + 2 * BS_;
    u16* Ab     = (u16*)(psum + (size_t)MP_ * PSL_);
    u16* Xb_all = Ab + (size_t)MP_ * KP_;
    u16* Wihb   = Xb_all + (size_t)MA_ * KP_;
    u16* Whhb   = Wihb + (size_t)NG_ * KP_;
    u16* Bb     = Whhb + (size_t)NG_ * KP_;
    u16* pb     = Bb + (size_t)NP_ * KP_;
    size_t need = (size_t)((char*)(pb + (size_t)BS_ * V_) - (char*)ws);
    if (ws_size < need) return;

    float* gate_out = out + (size_t)NS_ * B_ * T_ * V_;

    {
        const int R2 = MP_ * KP_ + (NP_ + 2 * NG_) * (KP_ / 8) + MA_ * (KP_ / 8);
        prep_all<<<(R2 + 255) / 256, 256, 0, stream>>>(eh, embW, Wih, Whh, sembW, tb, dom, sli,
                                                       hid, Ab, Bb, Wihb, Whhb, x_all, Xb_all);
    }
    gemm_setup<<<dim3(NG_ / 128, MA_ / 128 + MP_ / 128), 256, 0, stream>>>(
        Xb_all, Ab, Wihb, Whhb, gx_all, gh);

    for (int t = 0; t < T_; ++t) {
        const int cur = t & 1, prev = cur ^ 1;
        attn_fin<<<960, 256, 0, stream>>>(gx_all, gh, bih, bhh, hid, Ab, x_all,
                                          enc, story, Wr, Wrb, Wg, Wgb,
                                          prob2 + cur * BS_ * S_, sw2 + cur * BS_,
                                          gate_out, out, pb, psum,
                                          sw2 + prev * BS_, prob2 + prev * BS_ * S_, t);
        vocab_gh<<<412, 256, 0, stream>>>(Ab, Bb, Whhb, pb, psum, gh);
    }
    {
        const int last = (T_ - 1) & 1;
        scale_scatter<<<BS_, 256, 0, stream>>>(out, pb, psum, sw2 + last * BS_,
                                               prob2 + last * BS_ * S_, story);
    }
}